// Round 1
// baseline (1107.406 us; speedup 1.0000x reference)
//
#include <hip/hip_runtime.h>
#include <hip/hip_bf16.h>
#include <math.h>

#define NSEQ 4096
#define NP   4097          // padded length (pad=1 at front)
#define DIM  512
#define HEADS 8
#define DH   64
#define MLM  17            // landmarks
#define LCH  241           // 4097/17
#define KCONV 33

typedef __bf16 bf16_t;
typedef __bf16 bf16x8 __attribute__((ext_vector_type(8)));
typedef __bf16 bf16x4 __attribute__((ext_vector_type(4)));
typedef float  f32x4  __attribute__((ext_vector_type(4)));

// ---------------- LayerNorm + front-pad, write fp32 + bf16 ----------------
__global__ __launch_bounds__(128) void ln_kernel(const float* __restrict__ x,
        const float* __restrict__ nw, const float* __restrict__ nb,
        float* __restrict__ xf, bf16_t* __restrict__ xb)
{
    __shared__ float red[2];
    int i = blockIdx.x, t = threadIdx.x;
    if (i == 0) {  // padded zero row at front
        float4 z = {0.f,0.f,0.f,0.f};
        ((float4*)xf)[t] = z;
        bf16x4 bz; bz[0]=(__bf16)0.f; bz[1]=(__bf16)0.f; bz[2]=(__bf16)0.f; bz[3]=(__bf16)0.f;
        ((bf16x4*)xb)[t] = bz;
        return;
    }
    const float* xr = x + (size_t)(i-1)*DIM;
    float4 v = ((const float4*)xr)[t];
    float s = v.x+v.y+v.z+v.w;
    for (int o=32;o;o>>=1) s += __shfl_xor(s,o);
    if ((t&63)==0) red[t>>6] = s;
    __syncthreads();
    float mu = (red[0]+red[1]) * (1.f/DIM);
    __syncthreads();
    float dx=v.x-mu, dy=v.y-mu, dz=v.z-mu, dw=v.w-mu;
    float q = dx*dx+dy*dy+dz*dz+dw*dw;
    for (int o=32;o;o>>=1) q += __shfl_xor(q,o);
    if ((t&63)==0) red[t>>6] = q;
    __syncthreads();
    float var = (red[0]+red[1]) * (1.f/DIM);
    float inv = rsqrtf(var + 1e-5f);
    float4 wv = ((const float4*)nw)[t];
    float4 bv = ((const float4*)nb)[t];
    float o0 = dx*inv*wv.x + bv.x;
    float o1 = dy*inv*wv.y + bv.y;
    float o2 = dz*inv*wv.z + bv.z;
    float o3 = dw*inv*wv.w + bv.w;
    float4 ov = {o0,o1,o2,o3};
    ((float4*)(xf + (size_t)i*DIM))[t] = ov;
    bf16x4 ob; ob[0]=(__bf16)o0; ob[1]=(__bf16)o1; ob[2]=(__bf16)o2; ob[3]=(__bf16)o3;
    ((bf16x4*)(xb + (size_t)i*DIM))[t] = ob;
}

// ---------------- convert weights fp32 -> bf16 ----------------
__global__ __launch_bounds__(256) void cvt_w(const float* __restrict__ wqkv, const float* __restrict__ wout,
        bf16_t* __restrict__ wqkvb, bf16_t* __restrict__ woutb)
{
    int idx = blockIdx.x*256 + threadIdx.x;   // 0..262143
    const int n1 = (3*DIM*DIM)/4;             // 196608 float4 chunks
    if (idx < n1) {
        float4 v = ((const float4*)wqkv)[idx];
        bf16x4 b; b[0]=(__bf16)v.x; b[1]=(__bf16)v.y; b[2]=(__bf16)v.z; b[3]=(__bf16)v.w;
        ((bf16x4*)wqkvb)[idx] = b;
    } else {
        int k2 = idx - n1;                    // 0..65535
        float4 v = ((const float4*)wout)[k2];
        bf16x4 b; b[0]=(__bf16)v.x; b[1]=(__bf16)v.y; b[2]=(__bf16)v.z; b[3]=(__bf16)v.w;
        ((bf16x4*)woutb)[k2] = b;
    }
}

__global__ void init_zero(float* __restrict__ p, int n)
{
    int i = blockIdx.x*256 + threadIdx.x;
    if (i < n) p[i] = 0.f;
}

// ---------------- shared 128x128 bf16 MFMA GEMM core (C = A @ Bt^T) ----------------
__device__ inline void gemm_bt_128(const bf16_t* __restrict__ A, const bf16_t* __restrict__ Bt,
                                   int lda, int ldb, int row0, int col0,
                                   int K, int maxA, int maxB, f32x4 acc[4][4])
{
    __shared__ bf16_t As[128][40];   // stride 80B: 16B-aligned, conflict-benign
    __shared__ bf16_t Bs[128][40];
    const int t = threadIdx.x;
    const int lane = t & 63, wave = t >> 6;
    const int wm = wave >> 1, wn = wave & 1;
    const int lr = lane & 15, kq = (lane >> 4) * 8;
    const f32x4 fz = {0.f,0.f,0.f,0.f};
    #pragma unroll
    for (int m=0;m<4;m++)
        #pragma unroll
        for (int n=0;n<4;n++) acc[m][n] = fz;

    for (int k0 = 0; k0 < K; k0 += 32) {
        #pragma unroll
        for (int c = 0; c < 2; c++) {
            int cc = t + c*256;            // 0..511
            int r = cc >> 2, kk = (cc & 3) * 8;
            int ga = row0 + r; ga = ga > maxA ? maxA : ga;
            *(bf16x8*)&As[r][kk] = *(const bf16x8*)&A[(size_t)ga*lda + k0 + kk];
            int gb = col0 + r; gb = gb > maxB ? maxB : gb;
            *(bf16x8*)&Bs[r][kk] = *(const bf16x8*)&Bt[(size_t)gb*ldb + k0 + kk];
        }
        __syncthreads();
        bf16x8 af[4], bfv[4];
        #pragma unroll
        for (int m=0;m<4;m++) af[m] = *(const bf16x8*)&As[wm*64 + m*16 + lr][kq];
        #pragma unroll
        for (int n=0;n<4;n++) bfv[n] = *(const bf16x8*)&Bs[wn*64 + n*16 + lr][kq];
        #pragma unroll
        for (int m=0;m<4;m++)
            #pragma unroll
            for (int n=0;n<4;n++)
                acc[m][n] = __builtin_amdgcn_mfma_f32_16x16x32_bf16(af[m], bfv[n], acc[m][n], 0,0,0);
        __syncthreads();
    }
}

// ---------------- QKV GEMM: qkv = xnp @ Wqkv^T, split + scale + head layout ----------------
__global__ __launch_bounds__(256) void gemm_qkv(const bf16_t* __restrict__ xb, const bf16_t* __restrict__ wb,
        float* __restrict__ qf, float* __restrict__ kf, float* __restrict__ vf)
{
    f32x4 acc[4][4];
    int row0 = blockIdx.x*128, col0 = blockIdx.y*128;
    gemm_bt_128(xb, wb, DIM, DIM, row0, col0, DIM, NP-1, 3*DIM-1, acc);
    int t = threadIdx.x, lane = t&63, wave = t>>6, wm = wave>>1, wn = wave&1;
    #pragma unroll
    for (int m=0;m<4;m++) {
        int rb = row0 + wm*64 + m*16 + (lane>>4)*4;
        #pragma unroll
        for (int n=0;n<4;n++) {
            int cc = col0 + wn*64 + n*16 + (lane&15);
            int ts = cc >> 9, h = (cc >> 6) & 7, d = cc & 63;
            float scale = (ts==0) ? 0.125f : 1.f;   // q * dim_head^-0.5
            float* dst = (ts==0) ? qf : ((ts==1) ? kf : vf);
            size_t base = ((size_t)h*NP)*DH + d;
            #pragma unroll
            for (int j=0;j<4;j++) {
                int r = rb + j;
                if (r < NP) dst[base + (size_t)r*DH] = acc[m][n][j] * scale;
            }
        }
    }
}

// ---------------- landmark token means of xn (exact fp32 path) ----------------
__global__ __launch_bounds__(256) void lm_mean(const float* __restrict__ xf, float* __restrict__ xl)
{
    int m = blockIdx.x, t = threadIdx.x;
    const float* base = xf + (size_t)m*LCH*DIM;
    float s0=0.f, s1=0.f;
    #pragma unroll 4
    for (int j=0;j<LCH;j++) { s0 += base[(size_t)j*DIM + t]; s1 += base[(size_t)j*DIM + t + 256]; }
    xl[m*DIM + t]       = s0*(1.f/LCH);
    xl[m*DIM + t + 256] = s1*(1.f/LCH);
}

// ---------------- q_l / k_l = xl @ Wq^T / Wk^T (fp32, accurate for pinv path) ----------------
__global__ __launch_bounds__(256) void gemm_lm(const float* __restrict__ xl, const float* __restrict__ wqkv,
        float* __restrict__ qlf, float* __restrict__ klf)
{
    __shared__ float xs[DIM];
    int m = blockIdx.x, t = threadIdx.x;
    xs[t] = xl[m*DIM + t]; xs[t+256] = xl[m*DIM + t + 256];
    __syncthreads();
    float acc[4] = {0.f,0.f,0.f,0.f};
    const float* w0 = wqkv + (size_t)(t      )*DIM;
    const float* w1 = wqkv + (size_t)(t+256  )*DIM;
    const float* w2 = wqkv + (size_t)(t+512  )*DIM;
    const float* w3 = wqkv + (size_t)(t+768  )*DIM;
    for (int kk=0; kk<DIM; kk+=4) {
        float4 xv = *(const float4*)&xs[kk];
        float4 a0 = *(const float4*)&w0[kk]; acc[0] += xv.x*a0.x + xv.y*a0.y + xv.z*a0.z + xv.w*a0.w;
        float4 a1 = *(const float4*)&w1[kk]; acc[1] += xv.x*a1.x + xv.y*a1.y + xv.z*a1.z + xv.w*a1.w;
        float4 a2 = *(const float4*)&w2[kk]; acc[2] += xv.x*a2.x + xv.y*a2.y + xv.z*a2.z + xv.w*a2.w;
        float4 a3 = *(const float4*)&w3[kk]; acc[3] += xv.x*a3.x + xv.y*a3.y + xv.z*a3.z + xv.w*a3.w;
    }
    #pragma unroll
    for (int o=0;o<4;o++){
        int oc = t + o*256;
        int d = oc & 63;
        if (oc < DIM) { int h = oc>>6;       qlf[((size_t)h*MLM+m)*DH + d] = acc[o]*0.125f; }
        else          { int h = (oc-DIM)>>6; klf[((size_t)h*MLM+m)*DH + d] = acc[o]; }
    }
}

// ---------------- attn2 = softmax(q_l k_l^T) + global col/row max scalars ----------------
__global__ __launch_bounds__(320) void attn2_kernel(const float* __restrict__ qlf, const float* __restrict__ klf,
        float* __restrict__ a2g, unsigned* __restrict__ scal)
{
    __shared__ float qs[MLM][DH], ks[MLM][DH], a[MLM][MLM], rs[MLM], cs[MLM];
    int h = blockIdx.x, t = threadIdx.x;
    for (int c=t;c<MLM*DH;c+=320) { qs[c/DH][c%DH] = qlf[(size_t)h*MLM*DH + c];
                                    ks[c/DH][c%DH] = klf[(size_t)h*MLM*DH + c]; }
    __syncthreads();
    if (t < 289) {
        int m = t/17, n = t%17;
        float acc = 0.f;
        for (int d=0; d<DH; d++) acc += qs[m][d]*ks[n][d];
        a[m][n] = acc;
    }
    __syncthreads();
    if (t < 17) {
        float mx = -1e30f;
        for (int n=0;n<17;n++) mx = fmaxf(mx, a[t][n]);
        float s = 0.f;
        for (int n=0;n<17;n++) { float e = expf(a[t][n]-mx); a[t][n] = e; s += e; }
        float inv = 1.f/s;
        for (int n=0;n<17;n++) a[t][n] *= inv;
    }
    __syncthreads();
    if (t < 289) a2g[(size_t)h*289 + t] = a[t/17][t%17];
    if (t < 17) {
        float s=0.f, c2=0.f;
        for (int n=0;n<17;n++){ s += a[t][n]; c2 += a[n][t]; }
        rs[t] = s; cs[t] = c2;
    }
    __syncthreads();
    if (t == 0) {
        float mr=0.f, mc=0.f;
        for (int i2=0;i2<17;i2++){ mr=fmaxf(mr,rs[i2]); mc=fmaxf(mc,cs[i2]); }
        atomicMax(&scal[0], __float_as_uint(mr));
        atomicMax(&scal[1], __float_as_uint(mc));
    }
}

// ---------------- Moore-Penrose pinv iteration (17x17, fp32 in LDS) ----------------
__global__ __launch_bounds__(320) void pinv_kernel(const float* __restrict__ a2g, const unsigned* __restrict__ scal,
        float* __restrict__ zg)
{
    __shared__ float a[289], z[289], az[289], u[289], w[289];
    int h = blockIdx.x, t = threadIdx.x;
    if (t < 289) a[t] = a2g[(size_t)h*289 + t];
    __syncthreads();
    float cr = __uint_as_float(scal[0]) * __uint_as_float(scal[1]);
    if (t < 289) { int m=t/17, n=t%17; z[t] = a[n*17+m] / cr; }
    __syncthreads();
    for (int it=0; it<6; it++) {
        if (t < 289) { int m=t/17,n=t%17; float s=0.f; for(int p=0;p<17;p++) s += a[m*17+p]*z[p*17+n]; az[t]=s; }
        __syncthreads();
        if (t < 289) { int m=t/17,n=t%17; u[t] = ((m==n)?7.f:0.f) - az[t]; }
        __syncthreads();
        if (t < 289) { int m=t/17,n=t%17; float s=0.f; for(int p=0;p<17;p++) s += az[m*17+p]*u[p*17+n]; w[t] = ((m==n)?15.f:0.f) - s; }
        __syncthreads();
        if (t < 289) { int m=t/17,n=t%17; float s=0.f; for(int p=0;p<17;p++) s += az[m*17+p]*w[p*17+n]; u[t] = ((m==n)?13.f:0.f) - s; }
        __syncthreads();
        if (t < 289) { int m=t/17,n=t%17; float s=0.f; for(int p=0;p<17;p++) s += z[m*17+p]*u[p*17+n]; w[t] = 0.25f*s; }
        __syncthreads();
        if (t < 289) z[t] = w[t];
        __syncthreads();
    }
    if (t < 289) zg[(size_t)h*289 + t] = z[t];
}

// ---------------- S3 = exp(q_l k^T) (un-normalized attn3), transposed bf16 + row sums ----------------
__global__ __launch_bounds__(256) void s3_kernel(const float* __restrict__ qlf, const float* __restrict__ kf,
        bf16_t* __restrict__ s3t, float* __restrict__ sum3)
{
    __shared__ float qs[MLM][DH];
    int h = blockIdx.y, t = threadIdx.x;
    for (int c=t;c<MLM*DH;c+=256) qs[c/DH][c%DH] = qlf[(size_t)h*MLM*DH + c];
    __syncthreads();
    int j = blockIdx.x*256 + t;
    bool valid = j < NP;
    int jc = valid ? j : NP-1;
    const float* krow = kf + ((size_t)h*NP + jc)*DH;
    float4 kv[16];
    #pragma unroll
    for (int c=0;c<16;c++) kv[c] = ((const float4*)krow)[c];
    float e[17];
    #pragma unroll
    for (int m=0;m<17;m++) {
        float acc = 0.f;
        #pragma unroll
        for (int c=0;c<16;c++)
            acc += qs[m][4*c]*kv[c].x + qs[m][4*c+1]*kv[c].y + qs[m][4*c+2]*kv[c].z + qs[m][4*c+3]*kv[c].w;
        e[m] = valid ? expf(acc) : 0.f;   // logits are tiny (~N(0,0.065^2)); max-sub unnecessary
    }
    if (valid) {
        bf16_t* srow = s3t + ((size_t)h*NP + j)*32;
        bf16x8 v0, v1, v2, v3;
        #pragma unroll
        for (int q2=0;q2<8;q2++){ v0[q2]=(__bf16)e[q2]; v1[q2]=(__bf16)e[8+q2]; v2[q2]=(__bf16)0.f; v3[q2]=(__bf16)0.f; }
        v2[0] = (__bf16)e[16];
        *(bf16x8*)&srow[0]  = v0;
        *(bf16x8*)&srow[8]  = v1;
        *(bf16x8*)&srow[16] = v2;
        *(bf16x8*)&srow[24] = v3;
    }
    int lane = t & 63;
    #pragma unroll
    for (int m=0;m<17;m++) {
        float s = e[m];
        for (int o=32;o;o>>=1) s += __shfl_xor(s,o);
        if (lane==0) atomicAdd(&sum3[h*MLM+m], s);
    }
}

// ---------------- SB = S3 @ v (un-normalized), atomic partial sums ----------------
__global__ __launch_bounds__(256) void sb_kernel(const bf16_t* __restrict__ s3t, const float* __restrict__ vf,
        float* __restrict__ sb)
{
    int h = blockIdx.y, t = threadIdx.x;
    int d = t & 63, mg = t >> 6;
    float acc[5] = {0.f,0.f,0.f,0.f,0.f};
    int j0 = blockIdx.x * 256;
    int jend = j0 + 256 < NP ? j0 + 256 : NP;
    for (int j=j0; j<jend; j++) {
        float vv = vf[((size_t)h*NP + j)*DH + d];
        const bf16_t* srow = s3t + ((size_t)h*NP + j)*32;
        #pragma unroll
        for (int u2=0; u2<5; u2++) {
            int m = mg + 4*u2;
            if (m < 17) acc[u2] += (float)srow[m] * vv;
        }
    }
    #pragma unroll
    for (int u2=0; u2<5; u2++) {
        int m = mg + 4*u2;
        if (m < 17) atomicAdd(&sb[((size_t)h*MLM+m)*DH + d], acc[u2]);
    }
}

// ---------------- F2 = softmax(q k_l^T) @ Zinv @ diag(1/sum3), bf16 K-padded ----------------
__global__ __launch_bounds__(256) void f2_kernel(const float* __restrict__ qf, const float* __restrict__ klf,
        const float* __restrict__ zg, const float* __restrict__ sum3, bf16_t* __restrict__ f2)
{
    __shared__ float ks[MLM][DH];
    __shared__ float zs[289];
    __shared__ float si[MLM];
    int h = blockIdx.y, t = threadIdx.x;
    for (int c=t;c<MLM*DH;c+=256) ks[c/DH][c%DH] = klf[(size_t)h*MLM*DH + c];
    if (t < 289) zs[t] = zg[(size_t)h*289 + t];
    if (t < 17)  si[t] = 1.f / sum3[h*MLM + t];
    __syncthreads();
    int i = blockIdx.x*256 + t;
    bool valid = i < NP;
    int ic = valid ? i : NP-1;
    const float* qrow = qf + ((size_t)h*NP + ic)*DH;
    float4 qv[16];
    #pragma unroll
    for (int c=0;c<16;c++) qv[c] = ((const float4*)qrow)[c];
    float p[17];
    float mx = -1e30f;
    #pragma unroll
    for (int m=0;m<17;m++) {
        float acc = 0.f;
        #pragma unroll
        for (int c=0;c<16;c++)
            acc += ks[m][4*c]*qv[c].x + ks[m][4*c+1]*qv[c].y + ks[m][4*c+2]*qv[c].z + ks[m][4*c+3]*qv[c].w;
        p[m] = acc; mx = fmaxf(mx, acc);
    }
    float s = 0.f;
    #pragma unroll
    for (int m=0;m<17;m++) { p[m] = expf(p[m]-mx); s += p[m]; }
    float inv = 1.f/s;
    #pragma unroll
    for (int m=0;m<17;m++) p[m] *= inv;
    if (valid) {
        float f2v[17];
        #pragma unroll
        for (int mm=0;mm<17;mm++) {
            float acc = 0.f;
            #pragma unroll
            for (int t2=0;t2<17;t2++) acc += p[t2]*zs[t2*17+mm];
            f2v[mm] = acc * si[mm];
        }
        bf16_t* frow = f2 + ((size_t)h*NP + i)*32;
        bf16x8 v0, v1, v2, v3;
        #pragma unroll
        for (int q2=0;q2<8;q2++){ v0[q2]=(__bf16)f2v[q2]; v1[q2]=(__bf16)f2v[8+q2]; v2[q2]=(__bf16)0.f; v3[q2]=(__bf16)0.f; }
        v2[0] = (__bf16)f2v[16];
        *(bf16x8*)&frow[0]  = v0;
        *(bf16x8*)&frow[8]  = v1;
        *(bf16x8*)&frow[16] = v2;
        *(bf16x8*)&frow[24] = v3;
    }
}

// ---------------- head output: F2 @ SB + depthwise conv(v), -> bf16 [i][h*64+d] ----------------
__global__ __launch_bounds__(256) void headout_kernel(const bf16_t* __restrict__ f2, const float* __restrict__ sb,
        const float* __restrict__ vf, const float* __restrict__ cw, bf16_t* __restrict__ ocb)
{
    __shared__ float sbs[MLM][DH];
    __shared__ float cws[KCONV];
    int h = blockIdx.y, t = threadIdx.x;
    for (int c=t;c<MLM*DH;c+=256) sbs[c/DH][c%DH] = sb[(size_t)h*MLM*DH + c];
    if (t < KCONV) cws[t] = cw[h*KCONV + t];
    __syncthreads();
    int i = blockIdx.x*256 + t;
    if (i >= NP) return;
    float acc[64];
    #pragma unroll
    for (int d=0;d<64;d++) acc[d]=0.f;
    const float* vh = vf + (size_t)h*NP*DH;
    for (int s2=0;s2<KCONV;s2++) {
        int r = i + s2 - 16;
        if (r < 0 || r >= NP) continue;
        float c = cws[s2];
        const float4* vr = (const float4*)(vh + (size_t)r*DH);
        #pragma unroll
        for (int c4=0;c4<16;c4++) {
            float4 vv = vr[c4];
            acc[4*c4+0] += c*vv.x; acc[4*c4+1] += c*vv.y; acc[4*c4+2] += c*vv.z; acc[4*c4+3] += c*vv.w;
        }
    }
    const bf16_t* frow = f2 + ((size_t)h*NP + i)*32;
    #pragma unroll
    for (int m=0;m<17;m++) {
        float fv = (float)frow[m];
        #pragma unroll
        for (int d=0;d<64;d++) acc[d] += fv * sbs[m][d];
    }
    bf16_t* orow = ocb + (size_t)i*DIM + h*DH;
    #pragma unroll
    for (int c8=0;c8<8;c8++) {
        bf16x8 ov;
        #pragma unroll
        for (int q2=0;q2<8;q2++) ov[q2] = (__bf16)acc[8*c8+q2];
        *(bf16x8*)&orow[8*c8] = ov;
    }
}

// ---------------- out-proj GEMM + bias + residual + slice ----------------
__global__ __launch_bounds__(256) void gemm_out(const bf16_t* __restrict__ ocb, const bf16_t* __restrict__ wob,
        const float* __restrict__ x, const float* __restrict__ bo, float* __restrict__ out0)
{
    f32x4 acc[4][4];
    int row0 = blockIdx.x*128, col0 = blockIdx.y*128;
    gemm_bt_128(ocb, wob, DIM, DIM, row0, col0, DIM, NP-1, DIM-1, acc);
    int t = threadIdx.x, lane = t&63, wave = t>>6, wm = wave>>1, wn = wave&1;
    #pragma unroll
    for (int m=0;m<4;m++) {
        int rb = row0 + wm*64 + m*16 + (lane>>4)*4;
        #pragma unroll
        for (int n=0;n<4;n++) {
            int cc = col0 + wn*64 + n*16 + (lane&15);
            float bv = bo[cc];
            #pragma unroll
            for (int j=0;j<4;j++) {
                int r = rb + j;
                if (r >= 1 && r < NP)
                    out0[(size_t)(r-1)*DIM + cc] = x[(size_t)(r-1)*DIM + cc] + acc[m][n][j] + bv;
            }
        }
    }
}

// ---------------- the big one: attn = F2 @ S3 (K=32), 537 MB write-bound ----------------
__global__ __launch_bounds__(256) void attn_gemm(const bf16_t* __restrict__ f2, const bf16_t* __restrict__ s3t,
        float* __restrict__ attn)
{
    int h = blockIdx.z;
    int i0 = blockIdx.x*128, j0 = blockIdx.y*128;
    int t = threadIdx.x, lane = t&63, wave = t>>6;
    int wm = wave>>1, wn = wave&1;
    int lr = lane&15, kq = (lane>>4)*8;
    const bf16_t* Fh = f2  + (size_t)h*NP*32;
    const bf16_t* Sh = s3t + (size_t)h*NP*32;
    bf16x8 af[4], bv[4];
    #pragma unroll
    for (int m=0;m<4;m++){ int r = i0 + wm*64 + m*16 + lr; if (r > NP-1) r = NP-1; af[m] = *(const bf16x8*)&Fh[(size_t)r*32+kq]; }
    #pragma unroll
    for (int n=0;n<4;n++){ int c = j0 + wn*64 + n*16 + lr; if (c > NP-1) c = NP-1; bv[n] = *(const bf16x8*)&Sh[(size_t)c*32+kq]; }
    float* ah = attn + (size_t)h*NP*NP;
    const f32x4 fz = {0.f,0.f,0.f,0.f};
    #pragma unroll
    for (int m=0;m<4;m++){
        int rb = i0 + wm*64 + m*16 + (lane>>4)*4;
        #pragma unroll
        for (int n=0;n<4;n++){
            f32x4 acc = __builtin_amdgcn_mfma_f32_16x16x32_bf16(af[m], bv[n], fz, 0,0,0);
            int cc = j0 + wn*64 + n*16 + lr;
            if (cc < NP) {
                #pragma unroll
                for (int jj=0;jj<4;jj++){
                    int r = rb + jj;
                    if (r < NP) ah[(size_t)r*NP + cc] = acc[jj];
                }
            }
        }
    }
}

extern "C" void kernel_launch(void* const* d_in, const int* in_sizes, int n_in,
                              void* d_out, int out_size, void* d_ws, size_t ws_size,
                              hipStream_t stream)
{
    const float* x    = (const float*)d_in[0];
    const float* nw   = (const float*)d_in[1];
    const float* nb   = (const float*)d_in[2];
    const float* wqkv = (const float*)d_in[3];
    const float* wout = (const float*)d_in[4];
    const float* bo   = (const float*)d_in[5];
    const float* cw   = (const float*)d_in[6];
    float* out0 = (float*)d_out;
    float* attn = out0 + (size_t)NSEQ*DIM;

    char* w = (char*)d_ws;
    size_t off = 0;
    auto alloc = [&](size_t bytes)->char* {
        off = (off + 255) & ~(size_t)255;
        char* p = w + off; off += bytes; return p;
    };
    float*  xf     = (float*) alloc((size_t)NP*DIM*4);
    bf16_t* xb     = (bf16_t*)alloc((size_t)NP*DIM*2);
    bf16_t* wqkvb  = (bf16_t*)alloc((size_t)3*DIM*DIM*2);
    bf16_t* woutb  = (bf16_t*)alloc((size_t)DIM*DIM*2);
    float*  qf     = (float*) alloc((size_t)HEADS*NP*DH*4);
    float*  kf     = (float*) alloc((size_t)HEADS*NP*DH*4);
    float*  vf     = (float*) alloc((size_t)HEADS*NP*DH*4);
    float*  xl     = (float*) alloc((size_t)MLM*DIM*4);
    float*  qlf    = (float*) alloc((size_t)HEADS*MLM*DH*4);
    float*  klf    = (float*) alloc((size_t)HEADS*MLM*DH*4);
    float*  a2g    = (float*) alloc((size_t)HEADS*289*4);
    float*  zg     = (float*) alloc((size_t)HEADS*289*4);
    bf16_t* s3t    = (bf16_t*)alloc((size_t)HEADS*NP*32*2);
    bf16_t* f2     = (bf16_t*)alloc((size_t)HEADS*NP*32*2);
    bf16_t* ocb    = (bf16_t*)alloc((size_t)NP*DIM*2);
    // zero-initialized accumulators (contiguous)
    const int nzero = HEADS*MLM + HEADS*MLM*DH + 2;   // sum3 | SB | scal
    float* sum3 = (float*)alloc((size_t)nzero*4);
    float* sb   = sum3 + HEADS*MLM;
    unsigned* scal = (unsigned*)(sb + HEADS*MLM*DH);

    init_zero<<<(nzero+255)/256, 256, 0, stream>>>(sum3, nzero);
    ln_kernel<<<NP, 128, 0, stream>>>(x, nw, nb, xf, xb);
    cvt_w<<<1024, 256, 0, stream>>>(wqkv, wout, wqkvb, woutb);
    gemm_qkv<<<dim3(33,12), 256, 0, stream>>>(xb, wqkvb, qf, kf, vf);
    lm_mean<<<MLM, 256, 0, stream>>>(xf, xl);
    gemm_lm<<<MLM, 256, 0, stream>>>(xl, wqkv, qlf, klf);
    attn2_kernel<<<HEADS, 320, 0, stream>>>(qlf, klf, a2g, scal);
    pinv_kernel<<<HEADS, 320, 0, stream>>>(a2g, scal, zg);
    s3_kernel<<<dim3(17,HEADS), 256, 0, stream>>>(qlf, kf, s3t, sum3);
    sb_kernel<<<dim3(17,HEADS), 256, 0, stream>>>(s3t, vf, sb);
    f2_kernel<<<dim3(17,HEADS), 256, 0, stream>>>(qf, klf, zg, sum3, f2);
    headout_kernel<<<dim3(17,HEADS), 256, 0, stream>>>(f2, sb, vf, cw, ocb);
    gemm_out<<<dim3(33,4), 256, 0, stream>>>(ocb, woutb, x, bo, out0);
    attn_gemm<<<dim3(33,33,HEADS), 256, 0, stream>>>(f2, s3t, attn);
}